// Round 11
// baseline (206.411 us; speedup 1.0000x reference)
//
#include <hip/hip_runtime.h>

#define N_NODES 50000
#define N_EDGES 800000
#define N_GRAPHS 64
#define F_IN 6
#define HID 64
#define EMB 128

#define NBINS 196            // ceil(50000/256) bins of 256 dst nodes
#define EPB 4096             // edges per partition block
#define NCHUNK ((N_EDGES + EPB - 1) / EPB)   // 196
#define EPT (EPB / 256)      // 16 edges per thread

// ---- init: zero bin histogram ----
__global__ void k_init(int* __restrict__ bin_cnt) {
    if (threadIdx.x < NBINS + 4) bin_cnt[threadIdx.x] = 0;
}

// ---- coarse histogram: edges per 256-node dst bin (LDS-aggregated) ----
__global__ void k_binhist(const int* __restrict__ dst, int* __restrict__ bin_cnt) {
    __shared__ int lcnt[NBINS];
    for (int b = threadIdx.x; b < NBINS; b += 256) lcnt[b] = 0;
    __syncthreads();
    int e0 = blockIdx.x * EPB;
#pragma unroll
    for (int t = 0; t < EPT; ++t) {
        int e = e0 + t * 256 + threadIdx.x;
        if (e < N_EDGES) atomicAdd(&lcnt[dst[e] >> 8], 1);
    }
    __syncthreads();
    for (int b = threadIdx.x; b < NBINS; b += 256) {
        int c = lcnt[b];
        if (c) atomicAdd(&bin_cnt[b], c);
    }
}

// ---- scan of 196 bin counts; sentinels ----
__global__ void k_binscan(const int* __restrict__ bin_cnt, int* __restrict__ bin_start,
                          int* __restrict__ bin_pos, int* __restrict__ row_start) {
    __shared__ int s[256];
    int t = threadIdx.x;
    int v = (t < NBINS) ? bin_cnt[t] : 0;
    s[t] = v;
    __syncthreads();
    for (int off = 1; off < 256; off <<= 1) {
        int o = (t >= off) ? s[t - off] : 0;
        __syncthreads();
        s[t] += o;
        __syncthreads();
    }
    if (t < NBINS) { int st = s[t] - v; bin_start[t] = st; bin_pos[t] = st; }
    if (t == 0) { bin_start[NBINS] = N_EDGES; row_start[N_NODES] = N_EDGES; }
}

// ---- coarse partition: LDS-ranked, one range-reservation per (block,bin) ----
// rec = (src << 8) | (dst & 255)   [src < 65536]
__global__ void k_part(const int* __restrict__ src, const int* __restrict__ dst,
                       int* __restrict__ bin_pos, int* __restrict__ rec) {
    __shared__ int lcnt[NBINS];
    __shared__ int lbase[NBINS];
    for (int b = threadIdx.x; b < NBINS; b += 256) lcnt[b] = 0;
    __syncthreads();
    int e0 = blockIdx.x * EPB;
    int myBin[EPT], myRank[EPT], myRec[EPT];
#pragma unroll
    for (int t = 0; t < EPT; ++t) {
        int e = e0 + t * 256 + threadIdx.x;
        myBin[t] = -1;
        if (e < N_EDGES) {
            int d = dst[e];
            int s = src[e];
            int b = d >> 8;
            myBin[t] = b;
            myRec[t] = (s << 8) | (d & 255);
            myRank[t] = atomicAdd(&lcnt[b], 1);
        }
    }
    __syncthreads();
    for (int b = threadIdx.x; b < NBINS; b += 256) {
        int c = lcnt[b];
        lbase[b] = c ? atomicAdd(&bin_pos[b], c) : 0;
    }
    __syncthreads();
#pragma unroll
    for (int t = 0; t < EPT; ++t)
        if (myBin[t] >= 0) rec[lbase[myBin[t]] + myRank[t]] = myRec[t];
}

// ---- fused per-bin: degree hist + scan -> row_start/dinv/xs + fine scatter ----
__global__ void k_bdf(const int* __restrict__ rec, const int* __restrict__ bin_start,
                      const float* __restrict__ x, int* __restrict__ row_start,
                      float* __restrict__ dinv, float* __restrict__ xs,
                      int* __restrict__ eidx) {
    __shared__ int ldeg[256];
    __shared__ int rowb[256];
    int t = threadIdx.x;
    ldeg[t] = 0;
    __syncthreads();
    int beg = bin_start[blockIdx.x], end = bin_start[blockIdx.x + 1];
    for (int r = beg + t; r < end; r += 256)
        atomicAdd(&ldeg[rec[r] & 255], 1);
    __syncthreads();
    int v = ldeg[t];
    rowb[t] = v;
    __syncthreads();
    for (int off = 1; off < 256; off <<= 1) {
        int o = (t >= off) ? rowb[t - off] : 0;
        __syncthreads();
        rowb[t] += o;
        __syncthreads();
    }
    int rb = beg + rowb[t] - v;          // exclusive start for local node t
    rowb[t] = rb;                        // own-index write, no hazard
    ldeg[t] = 0;                         // reuse as scatter cursor
    int node = blockIdx.x * 256 + t;
    if (node < N_NODES) {
        row_start[node] = rb;
        float dv = rsqrtf((float)(v + 1));            // +1 = self-loop
        dinv[node] = dv;
#pragma unroll
        for (int k = 0; k < F_IN; ++k) xs[node * F_IN + k] = x[node * F_IN + k] * dv;
    }
    __syncthreads();
    for (int r = beg + t; r < end; r += 256) {
        int rc = rec[r];
        int ld = rc & 255;
        int p = atomicAdd(&ldeg[ld], 1);
        eidx[rowb[ld] + p] = rc >> 8;
    }
}

__device__ __forceinline__ float bcast(float v, int lane) {
    return __int_as_float(__builtin_amdgcn_readlane(__float_as_int(v), lane));
}

#define PB 1280   // persistent blocks for fused layer kernels

// ---- fused layer1+mm2: agg(xs) -> relu(@W1+b1) -> h2' = (out@W2)*dinv ----
__global__ void k_l1mm(const float* __restrict__ xs, const int* __restrict__ row_start,
                       const int* __restrict__ eidx, const float* __restrict__ dinv,
                       const float* __restrict__ W1, const float* __restrict__ b1,
                       const float* __restrict__ W2, float* __restrict__ hout) {
    __shared__ float sW[F_IN * HID];
    __shared__ float sB[HID];
    for (int i = threadIdx.x; i < F_IN * HID; i += 256) sW[i] = W1[i];
    if (threadIdx.x < HID) sB[threadIdx.x] = b1[threadIdx.x];
    __syncthreads();
    int f = threadIdx.x & 63;
    float wk[HID];                       // W2 column f, loaded once per wave
#pragma unroll
    for (int k = 0; k < HID; ++k) wk[k] = W2[k * HID + f];
    bool act = (f < F_IN);
    int wv = blockIdx.x * 4 + (threadIdx.x >> 6);
    for (int node = wv; node < N_NODES; node += PB * 4) {
        int beg = __builtin_amdgcn_readfirstlane(row_start[node]);
        int end = __builtin_amdgcn_readfirstlane(row_start[node + 1]);
        float sum = 0.0f;
        int j = beg;
        for (; j + 8 <= end; j += 8) {
            int s0 = eidx[j+0], s1 = eidx[j+1], s2 = eidx[j+2], s3 = eidx[j+3];
            int s4 = eidx[j+4], s5 = eidx[j+5], s6 = eidx[j+6], s7 = eidx[j+7];
            if (act) {
                float v0 = xs[s0 * F_IN + f], v1 = xs[s1 * F_IN + f];
                float v2 = xs[s2 * F_IN + f], v3 = xs[s3 * F_IN + f];
                float v4 = xs[s4 * F_IN + f], v5 = xs[s5 * F_IN + f];
                float v6 = xs[s6 * F_IN + f], v7 = xs[s7 * F_IN + f];
                sum += ((v0 + v1) + (v2 + v3)) + ((v4 + v5) + (v6 + v7));
            }
        }
        for (; j < end; ++j) {
            int s = eidx[j];
            if (act) sum += xs[s * F_IN + f];
        }
        float dv = dinv[node];
        float val = act ? (sum + xs[node * F_IN + f]) * dv : 0.0f;
        float o = sB[f];
        o = fmaf(bcast(val, 0), sW[0 * HID + f], o);
        o = fmaf(bcast(val, 1), sW[1 * HID + f], o);
        o = fmaf(bcast(val, 2), sW[2 * HID + f], o);
        o = fmaf(bcast(val, 3), sW[3 * HID + f], o);
        o = fmaf(bcast(val, 4), sW[4 * HID + f], o);
        o = fmaf(bcast(val, 5), sW[5 * HID + f], o);
        o = fmaxf(o, 0.0f);              // layer-1 output, lane f
        // mm2 epilogue: h2'[f] = (sum_k o_k * W2[k][f]) * dv
        float a0 = 0.0f, a1 = 0.0f, a2 = 0.0f, a3 = 0.0f;
#pragma unroll
        for (int k = 0; k < HID; k += 4) {
            a0 = fmaf(bcast(o, k + 0), wk[k + 0], a0);
            a1 = fmaf(bcast(o, k + 1), wk[k + 1], a1);
            a2 = fmaf(bcast(o, k + 2), wk[k + 2], a2);
            a3 = fmaf(bcast(o, k + 3), wk[k + 3], a3);
        }
        hout[node * HID + f] = ((a0 + a1) + (a2 + a3)) * dv;
    }
}

// ---- fused gather+mm3: agg(h2') -> relu(+b2) -> h3' = (out@W3)*dinv ----
__global__ void k_gmm(const float* __restrict__ h, const int* __restrict__ row_start,
                      const int* __restrict__ eidx, const float* __restrict__ dinv,
                      const float* __restrict__ b2, const float* __restrict__ W3,
                      float* __restrict__ hout) {
    int f = threadIdx.x & 63;
    float wk[HID];                       // W3 column f
#pragma unroll
    for (int k = 0; k < HID; ++k) wk[k] = W3[k * HID + f];
    float bv = b2[f];
    int wv = blockIdx.x * 4 + (threadIdx.x >> 6);
    for (int node = wv; node < N_NODES; node += PB * 4) {
        int beg = __builtin_amdgcn_readfirstlane(row_start[node]);
        int end = __builtin_amdgcn_readfirstlane(row_start[node + 1]);
        float sum = 0.0f;
        int j = beg;
        for (; j + 8 <= end; j += 8) {
            int s0 = eidx[j+0], s1 = eidx[j+1], s2 = eidx[j+2], s3 = eidx[j+3];
            int s4 = eidx[j+4], s5 = eidx[j+5], s6 = eidx[j+6], s7 = eidx[j+7];
            float v0 = h[s0 * HID + f], v1 = h[s1 * HID + f];
            float v2 = h[s2 * HID + f], v3 = h[s3 * HID + f];
            float v4 = h[s4 * HID + f], v5 = h[s5 * HID + f];
            float v6 = h[s6 * HID + f], v7 = h[s7 * HID + f];
            sum += ((v0 + v1) + (v2 + v3)) + ((v4 + v5) + (v6 + v7));
        }
        if (j + 4 <= end) {
            int s0 = eidx[j+0], s1 = eidx[j+1], s2 = eidx[j+2], s3 = eidx[j+3];
            float v0 = h[s0 * HID + f], v1 = h[s1 * HID + f];
            float v2 = h[s2 * HID + f], v3 = h[s3 * HID + f];
            sum += ((v0 + v1) + (v2 + v3));
            j += 4;
        }
        for (; j < end; ++j) sum += h[eidx[j] * HID + f];
        sum += h[node * HID + f];
        float dv = dinv[node];
        float o = fmaxf(fmaf(sum, dv, bv), 0.0f);    // layer-2 output, lane f
        // mm3 epilogue
        float a0 = 0.0f, a1 = 0.0f, a2 = 0.0f, a3 = 0.0f;
#pragma unroll
        for (int k = 0; k < HID; k += 4) {
            a0 = fmaf(bcast(o, k + 0), wk[k + 0], a0);
            a1 = fmaf(bcast(o, k + 1), wk[k + 1], a1);
            a2 = fmaf(bcast(o, k + 2), wk[k + 2], a2);
            a3 = fmaf(bcast(o, k + 3), wk[k + 3], a3);
        }
        hout[node * HID + f] = ((a0 + a1) + (a2 + a3)) * dv;
    }
}

// ---- final per-node gather: out = relu(dinv*(sum h3'[s] + h3'[d]) + b3) ----
__global__ void k_gather(const float* __restrict__ h, const int* __restrict__ row_start,
                         const int* __restrict__ eidx, const float* __restrict__ dinv,
                         const float* __restrict__ b, float* __restrict__ out) {
    int node = (blockIdx.x * blockDim.x + threadIdx.x) >> 6;
    int f = threadIdx.x & 63;
    if (node >= N_NODES) return;
    int beg = __builtin_amdgcn_readfirstlane(row_start[node]);
    int end = __builtin_amdgcn_readfirstlane(row_start[node + 1]);
    float sum = 0.0f;
    int j = beg;
    for (; j + 8 <= end; j += 8) {
        int s0 = eidx[j+0], s1 = eidx[j+1], s2 = eidx[j+2], s3 = eidx[j+3];
        int s4 = eidx[j+4], s5 = eidx[j+5], s6 = eidx[j+6], s7 = eidx[j+7];
        float v0 = h[s0 * HID + f], v1 = h[s1 * HID + f];
        float v2 = h[s2 * HID + f], v3 = h[s3 * HID + f];
        float v4 = h[s4 * HID + f], v5 = h[s5 * HID + f];
        float v6 = h[s6 * HID + f], v7 = h[s7 * HID + f];
        sum += ((v0 + v1) + (v2 + v3)) + ((v4 + v5) + (v6 + v7));
    }
    if (j + 4 <= end) {
        int s0 = eidx[j+0], s1 = eidx[j+1], s2 = eidx[j+2], s3 = eidx[j+3];
        float v0 = h[s0 * HID + f], v1 = h[s1 * HID + f];
        float v2 = h[s2 * HID + f], v3 = h[s3 * HID + f];
        sum += ((v0 + v1) + (v2 + v3));
        j += 4;
    }
    for (; j < end; ++j) sum += h[eidx[j] * HID + f];
    sum += h[node * HID + f];
    out[node * HID + f] = fmaxf(fmaf(sum, dinv[node], b[f]), 0.0f);
}

// ---- fused pool+FC: one block per graph (batch sorted -> binary search) ----
__global__ void k_poolfc(const float* __restrict__ xn, const int* __restrict__ batch,
                         const float* __restrict__ Wfc, const float* __restrict__ bfc,
                         float* __restrict__ out) {
    __shared__ float ssum[4][HID];
    __shared__ float sg[HID];
    __shared__ int bounds[2];
    int g = blockIdx.x;
    int t = threadIdx.x;
    if (t < 2) {
        int target = g + t;
        int lo = 0, hi = N_NODES;
        while (lo < hi) { int mid = (lo + hi) >> 1; if (batch[mid] < target) lo = mid + 1; else hi = mid; }
        bounds[t] = lo;
    }
    __syncthreads();
    int lo = bounds[0], hi = bounds[1];
    int f = t & 63, w = t >> 6;
    float sum = 0.0f;
    for (int n = lo + w; n < hi; n += 4) sum += xn[n * HID + f];
    ssum[w][f] = sum;
    __syncthreads();
    if (t < HID) {
        float inv = 1.0f / fmaxf((float)(hi - lo), 1.0f);
        sg[t] = (ssum[0][t] + ssum[1][t] + ssum[2][t] + ssum[3][t]) * inv;
    }
    __syncthreads();
    if (t < EMB) {
        float s = bfc[t];
#pragma unroll 8
        for (int k = 0; k < HID; ++k) s = fmaf(sg[k], Wfc[k * EMB + t], s);
        out[g * EMB + t] = fmaxf(s, 0.0f);
    }
}

extern "C" void kernel_launch(void* const* d_in, const int* in_sizes, int n_in,
                              void* d_out, int out_size, void* d_ws, size_t ws_size,
                              hipStream_t stream) {
    const float* x    = (const float*)d_in[0];
    const int*   ei   = (const int*)d_in[1];
    const int*   batch= (const int*)d_in[2];
    const float* W1   = (const float*)d_in[3];
    const float* b1   = (const float*)d_in[4];
    const float* W2   = (const float*)d_in[5];
    const float* b2   = (const float*)d_in[6];
    const float* W3   = (const float*)d_in[7];
    const float* b3   = (const float*)d_in[8];
    const float* Wfc  = (const float*)d_in[9];
    const float* bfc  = (const float*)d_in[10];
    float* out = (float*)d_out;

    // workspace layout (4-byte words)
    float* ws        = (float*)d_ws;
    float* dinv      = ws;                                 // 50048
    float* h         = ws + 50048;                         // 3.2M  (h2' / out3)
    float* xcur      = h + N_NODES * HID;                  // 3.2M  (h3')
    float* xs        = xcur + N_NODES * HID;               // 300032
    int*   row_start = (int*)(xs + 300032);                // 50176
    int*   bin_cnt   = row_start + 50176;                  // 256
    int*   bin_start = bin_cnt + 256;                      // 256
    int*   bin_pos   = bin_start + 256;                    // 256
    int*   rec       = bin_pos + 256;                      // 800000
    int*   eidx      = rec + 800000;                       // 800000

    const int* src = ei;
    const int* dst = ei + N_EDGES;

    const int B = 256;
    const int gNF = (N_NODES * HID + B - 1) / B;

    // CSR build (5 dispatches)
    k_init<<<1, B, 0, stream>>>(bin_cnt);
    k_binhist<<<NCHUNK, B, 0, stream>>>(dst, bin_cnt);
    k_binscan<<<1, B, 0, stream>>>(bin_cnt, bin_start, bin_pos, row_start);
    k_part<<<NCHUNK, B, 0, stream>>>(src, dst, bin_pos, rec);
    k_bdf<<<NBINS, B, 0, stream>>>(rec, bin_start, x, row_start, dinv, xs, eidx);

    // layer 1 + mm2 fused -> h2'
    k_l1mm<<<PB, B, 0, stream>>>(xs, row_start, eidx, dinv, W1, b1, W2, h);
    // layer 2 gather + mm3 fused -> h3'
    k_gmm<<<PB, B, 0, stream>>>(h, row_start, eidx, dinv, b2, W3, xcur);
    // layer 3 gather -> out3
    k_gather<<<gNF, B, 0, stream>>>(xcur, row_start, eidx, dinv, b3, h);

    // pool + FC fused (one block per graph, no atomics)
    k_poolfc<<<N_GRAPHS, B, 0, stream>>>(h, batch, Wfc, bfc, out);
}

// Round 12
// 205.191 us; speedup vs baseline: 1.0059x; 1.0059x over previous
//
#include <hip/hip_runtime.h>

#define N_NODES 50000
#define N_EDGES 800000
#define N_GRAPHS 64
#define F_IN 6
#define HID 64
#define EMB 128

#define NBINS 196            // ceil(50000/256) bins of 256 dst nodes
#define EPB 4096             // edges per partition block
#define NCHUNK ((N_EDGES + EPB - 1) / EPB)   // 196
#define EPT (EPB / 256)      // 16 edges per thread

// ---- init: zero bin histogram ----
__global__ void k_init(int* __restrict__ bin_cnt) {
    if (threadIdx.x < NBINS + 4) bin_cnt[threadIdx.x] = 0;
}

// ---- coarse histogram: edges per 256-node dst bin (LDS-aggregated) ----
__global__ void k_binhist(const int* __restrict__ dst, int* __restrict__ bin_cnt) {
    __shared__ int lcnt[NBINS];
    for (int b = threadIdx.x; b < NBINS; b += 256) lcnt[b] = 0;
    __syncthreads();
    int e0 = blockIdx.x * EPB;
#pragma unroll
    for (int t = 0; t < EPT; ++t) {
        int e = e0 + t * 256 + threadIdx.x;
        if (e < N_EDGES) atomicAdd(&lcnt[dst[e] >> 8], 1);
    }
    __syncthreads();
    for (int b = threadIdx.x; b < NBINS; b += 256) {
        int c = lcnt[b];
        if (c) atomicAdd(&bin_cnt[b], c);
    }
}

// ---- scan of 196 bin counts; sentinels ----
__global__ void k_binscan(const int* __restrict__ bin_cnt, int* __restrict__ bin_start,
                          int* __restrict__ bin_pos, int* __restrict__ row_start) {
    __shared__ int s[256];
    int t = threadIdx.x;
    int v = (t < NBINS) ? bin_cnt[t] : 0;
    s[t] = v;
    __syncthreads();
    for (int off = 1; off < 256; off <<= 1) {
        int o = (t >= off) ? s[t - off] : 0;
        __syncthreads();
        s[t] += o;
        __syncthreads();
    }
    if (t < NBINS) { int st = s[t] - v; bin_start[t] = st; bin_pos[t] = st; }
    if (t == 0) { bin_start[NBINS] = N_EDGES; row_start[N_NODES] = N_EDGES; }
}

// ---- coarse partition: LDS-ranked, one range-reservation per (block,bin) ----
// rec = (src << 8) | (dst & 255)   [src < 65536]
__global__ void k_part(const int* __restrict__ src, const int* __restrict__ dst,
                       int* __restrict__ bin_pos, int* __restrict__ rec) {
    __shared__ int lcnt[NBINS];
    __shared__ int lbase[NBINS];
    for (int b = threadIdx.x; b < NBINS; b += 256) lcnt[b] = 0;
    __syncthreads();
    int e0 = blockIdx.x * EPB;
    int myBin[EPT], myRank[EPT], myRec[EPT];
#pragma unroll
    for (int t = 0; t < EPT; ++t) {
        int e = e0 + t * 256 + threadIdx.x;
        myBin[t] = -1;
        if (e < N_EDGES) {
            int d = dst[e];
            int s = src[e];
            int b = d >> 8;
            myBin[t] = b;
            myRec[t] = (s << 8) | (d & 255);
            myRank[t] = atomicAdd(&lcnt[b], 1);
        }
    }
    __syncthreads();
    for (int b = threadIdx.x; b < NBINS; b += 256) {
        int c = lcnt[b];
        lbase[b] = c ? atomicAdd(&bin_pos[b], c) : 0;
    }
    __syncthreads();
#pragma unroll
    for (int t = 0; t < EPT; ++t)
        if (myBin[t] >= 0) rec[lbase[myBin[t]] + myRank[t]] = myRec[t];
}

// ---- fused per-bin: degree hist + scan -> row_start/dinv/xs + fine scatter ----
__global__ void k_bdf(const int* __restrict__ rec, const int* __restrict__ bin_start,
                      const float* __restrict__ x, int* __restrict__ row_start,
                      float* __restrict__ dinv, float* __restrict__ xs,
                      int* __restrict__ eidx) {
    __shared__ int ldeg[256];
    __shared__ int rowb[256];
    int t = threadIdx.x;
    ldeg[t] = 0;
    __syncthreads();
    int beg = bin_start[blockIdx.x], end = bin_start[blockIdx.x + 1];
    for (int r = beg + t; r < end; r += 256)
        atomicAdd(&ldeg[rec[r] & 255], 1);
    __syncthreads();
    int v = ldeg[t];
    rowb[t] = v;
    __syncthreads();
    for (int off = 1; off < 256; off <<= 1) {
        int o = (t >= off) ? rowb[t - off] : 0;
        __syncthreads();
        rowb[t] += o;
        __syncthreads();
    }
    int rb = beg + rowb[t] - v;          // exclusive start for local node t
    rowb[t] = rb;                        // own-index write, no hazard
    ldeg[t] = 0;                         // reuse as scatter cursor
    int node = blockIdx.x * 256 + t;
    if (node < N_NODES) {
        row_start[node] = rb;
        float dv = rsqrtf((float)(v + 1));            // +1 = self-loop
        dinv[node] = dv;
#pragma unroll
        for (int k = 0; k < F_IN; ++k) xs[node * F_IN + k] = x[node * F_IN + k] * dv;
    }
    __syncthreads();
    for (int r = beg + t; r < end; r += 256) {
        int rc = rec[r];
        int ld = rc & 255;
        int p = atomicAdd(&ldeg[ld], 1);
        eidx[rowb[ld] + p] = rc >> 8;
    }
}

__device__ __forceinline__ float bcast(float v, int lane) {
    return __int_as_float(__builtin_amdgcn_readlane(__float_as_int(v), lane));
}

#define PB 1280   // persistent blocks for fused layer kernels

// ---- fused layer1+mm2: agg(xs) -> relu(@W1+b1) -> h2' = (out@W2)*dinv ----
__global__ void k_l1mm(const float* __restrict__ xs, const int* __restrict__ row_start,
                       const int* __restrict__ eidx, const float* __restrict__ dinv,
                       const float* __restrict__ W1, const float* __restrict__ b1,
                       const float* __restrict__ W2, float* __restrict__ hout) {
    __shared__ float sW[F_IN * HID];
    __shared__ float sB[HID];
    for (int i = threadIdx.x; i < F_IN * HID; i += 256) sW[i] = W1[i];
    if (threadIdx.x < HID) sB[threadIdx.x] = b1[threadIdx.x];
    __syncthreads();
    int f = threadIdx.x & 63;
    float wk[HID];                       // W2 column f, loaded once per wave
#pragma unroll
    for (int k = 0; k < HID; ++k) wk[k] = W2[k * HID + f];
    bool act = (f < F_IN);
    int wv = blockIdx.x * 4 + (threadIdx.x >> 6);
    for (int node = wv; node < N_NODES; node += PB * 4) {
        int beg = __builtin_amdgcn_readfirstlane(row_start[node]);
        int end = __builtin_amdgcn_readfirstlane(row_start[node + 1]);
        float sum = 0.0f;
        int j = beg;
        for (; j + 8 <= end; j += 8) {
            int s0 = eidx[j+0], s1 = eidx[j+1], s2 = eidx[j+2], s3 = eidx[j+3];
            int s4 = eidx[j+4], s5 = eidx[j+5], s6 = eidx[j+6], s7 = eidx[j+7];
            if (act) {
                float v0 = xs[s0 * F_IN + f], v1 = xs[s1 * F_IN + f];
                float v2 = xs[s2 * F_IN + f], v3 = xs[s3 * F_IN + f];
                float v4 = xs[s4 * F_IN + f], v5 = xs[s5 * F_IN + f];
                float v6 = xs[s6 * F_IN + f], v7 = xs[s7 * F_IN + f];
                sum += ((v0 + v1) + (v2 + v3)) + ((v4 + v5) + (v6 + v7));
            }
        }
        for (; j < end; ++j) {
            int s = eidx[j];
            if (act) sum += xs[s * F_IN + f];
        }
        float dv = dinv[node];
        float val = act ? (sum + xs[node * F_IN + f]) * dv : 0.0f;
        float o = sB[f];
        o = fmaf(bcast(val, 0), sW[0 * HID + f], o);
        o = fmaf(bcast(val, 1), sW[1 * HID + f], o);
        o = fmaf(bcast(val, 2), sW[2 * HID + f], o);
        o = fmaf(bcast(val, 3), sW[3 * HID + f], o);
        o = fmaf(bcast(val, 4), sW[4 * HID + f], o);
        o = fmaf(bcast(val, 5), sW[5 * HID + f], o);
        o = fmaxf(o, 0.0f);              // layer-1 output, lane f
        // mm2 epilogue: h2'[f] = (sum_k o_k * W2[k][f]) * dv
        float a0 = 0.0f, a1 = 0.0f, a2 = 0.0f, a3 = 0.0f;
#pragma unroll
        for (int k = 0; k < HID; k += 4) {
            a0 = fmaf(bcast(o, k + 0), wk[k + 0], a0);
            a1 = fmaf(bcast(o, k + 1), wk[k + 1], a1);
            a2 = fmaf(bcast(o, k + 2), wk[k + 2], a2);
            a3 = fmaf(bcast(o, k + 3), wk[k + 3], a3);
        }
        hout[node * HID + f] = ((a0 + a1) + (a2 + a3)) * dv;
    }
}

// ---- fused gather+mm3: agg(h2') -> relu(+b2) -> h3' = (out@W3)*dinv ----
__global__ void k_gmm(const float* __restrict__ h, const int* __restrict__ row_start,
                      const int* __restrict__ eidx, const float* __restrict__ dinv,
                      const float* __restrict__ b2, const float* __restrict__ W3,
                      float* __restrict__ hout) {
    int f = threadIdx.x & 63;
    float wk[HID];                       // W3 column f
#pragma unroll
    for (int k = 0; k < HID; ++k) wk[k] = W3[k * HID + f];
    float bv = b2[f];
    int wv = blockIdx.x * 4 + (threadIdx.x >> 6);
    for (int node = wv; node < N_NODES; node += PB * 4) {
        int beg = __builtin_amdgcn_readfirstlane(row_start[node]);
        int end = __builtin_amdgcn_readfirstlane(row_start[node + 1]);
        float sum = 0.0f;
        int j = beg;
        for (; j + 8 <= end; j += 8) {
            int s0 = eidx[j+0], s1 = eidx[j+1], s2 = eidx[j+2], s3 = eidx[j+3];
            int s4 = eidx[j+4], s5 = eidx[j+5], s6 = eidx[j+6], s7 = eidx[j+7];
            float v0 = h[s0 * HID + f], v1 = h[s1 * HID + f];
            float v2 = h[s2 * HID + f], v3 = h[s3 * HID + f];
            float v4 = h[s4 * HID + f], v5 = h[s5 * HID + f];
            float v6 = h[s6 * HID + f], v7 = h[s7 * HID + f];
            sum += ((v0 + v1) + (v2 + v3)) + ((v4 + v5) + (v6 + v7));
        }
        if (j + 4 <= end) {
            int s0 = eidx[j+0], s1 = eidx[j+1], s2 = eidx[j+2], s3 = eidx[j+3];
            float v0 = h[s0 * HID + f], v1 = h[s1 * HID + f];
            float v2 = h[s2 * HID + f], v3 = h[s3 * HID + f];
            sum += ((v0 + v1) + (v2 + v3));
            j += 4;
        }
        for (; j < end; ++j) sum += h[eidx[j] * HID + f];
        sum += h[node * HID + f];
        float dv = dinv[node];
        float o = fmaxf(fmaf(sum, dv, bv), 0.0f);    // layer-2 output, lane f
        // mm3 epilogue
        float a0 = 0.0f, a1 = 0.0f, a2 = 0.0f, a3 = 0.0f;
#pragma unroll
        for (int k = 0; k < HID; k += 4) {
            a0 = fmaf(bcast(o, k + 0), wk[k + 0], a0);
            a1 = fmaf(bcast(o, k + 1), wk[k + 1], a1);
            a2 = fmaf(bcast(o, k + 2), wk[k + 2], a2);
            a3 = fmaf(bcast(o, k + 3), wk[k + 3], a3);
        }
        hout[node * HID + f] = ((a0 + a1) + (a2 + a3)) * dv;
    }
}

// ---- final per-node gather: out = relu(dinv*(sum h3'[s] + h3'[d]) + b3) ----
__global__ void k_gather(const float* __restrict__ h, const int* __restrict__ row_start,
                         const int* __restrict__ eidx, const float* __restrict__ dinv,
                         const float* __restrict__ b, float* __restrict__ out) {
    int node = (blockIdx.x * blockDim.x + threadIdx.x) >> 6;
    int f = threadIdx.x & 63;
    if (node >= N_NODES) return;
    int beg = __builtin_amdgcn_readfirstlane(row_start[node]);
    int end = __builtin_amdgcn_readfirstlane(row_start[node + 1]);
    float sum = 0.0f;
    int j = beg;
    for (; j + 8 <= end; j += 8) {
        int s0 = eidx[j+0], s1 = eidx[j+1], s2 = eidx[j+2], s3 = eidx[j+3];
        int s4 = eidx[j+4], s5 = eidx[j+5], s6 = eidx[j+6], s7 = eidx[j+7];
        float v0 = h[s0 * HID + f], v1 = h[s1 * HID + f];
        float v2 = h[s2 * HID + f], v3 = h[s3 * HID + f];
        float v4 = h[s4 * HID + f], v5 = h[s5 * HID + f];
        float v6 = h[s6 * HID + f], v7 = h[s7 * HID + f];
        sum += ((v0 + v1) + (v2 + v3)) + ((v4 + v5) + (v6 + v7));
    }
    if (j + 4 <= end) {
        int s0 = eidx[j+0], s1 = eidx[j+1], s2 = eidx[j+2], s3 = eidx[j+3];
        float v0 = h[s0 * HID + f], v1 = h[s1 * HID + f];
        float v2 = h[s2 * HID + f], v3 = h[s3 * HID + f];
        sum += ((v0 + v1) + (v2 + v3));
        j += 4;
    }
    for (; j < end; ++j) sum += h[eidx[j] * HID + f];
    sum += h[node * HID + f];
    out[node * HID + f] = fmaxf(fmaf(sum, dinv[node], b[f]), 0.0f);
}

// ---- fused pool+FC: one block per graph (batch sorted -> binary search) ----
__global__ void k_poolfc(const float* __restrict__ xn, const int* __restrict__ batch,
                         const float* __restrict__ Wfc, const float* __restrict__ bfc,
                         float* __restrict__ out) {
    __shared__ float ssum[4][HID];
    __shared__ float sg[HID];
    __shared__ int bounds[2];
    int g = blockIdx.x;
    int t = threadIdx.x;
    if (t < 2) {
        int target = g + t;
        int lo = 0, hi = N_NODES;
        while (lo < hi) { int mid = (lo + hi) >> 1; if (batch[mid] < target) lo = mid + 1; else hi = mid; }
        bounds[t] = lo;
    }
    __syncthreads();
    int lo = bounds[0], hi = bounds[1];
    int f = t & 63, w = t >> 6;
    float sum = 0.0f;
    for (int n = lo + w; n < hi; n += 4) sum += xn[n * HID + f];
    ssum[w][f] = sum;
    __syncthreads();
    if (t < HID) {
        float inv = 1.0f / fmaxf((float)(hi - lo), 1.0f);
        sg[t] = (ssum[0][t] + ssum[1][t] + ssum[2][t] + ssum[3][t]) * inv;
    }
    __syncthreads();
    if (t < EMB) {
        float s = bfc[t];
#pragma unroll 8
        for (int k = 0; k < HID; ++k) s = fmaf(sg[k], Wfc[k * EMB + t], s);
        out[g * EMB + t] = fmaxf(s, 0.0f);
    }
}

extern "C" void kernel_launch(void* const* d_in, const int* in_sizes, int n_in,
                              void* d_out, int out_size, void* d_ws, size_t ws_size,
                              hipStream_t stream) {
    const float* x    = (const float*)d_in[0];
    const int*   ei   = (const int*)d_in[1];
    const int*   batch= (const int*)d_in[2];
    const float* W1   = (const float*)d_in[3];
    const float* b1   = (const float*)d_in[4];
    const float* W2   = (const float*)d_in[5];
    const float* b2   = (const float*)d_in[6];
    const float* W3   = (const float*)d_in[7];
    const float* b3   = (const float*)d_in[8];
    const float* Wfc  = (const float*)d_in[9];
    const float* bfc  = (const float*)d_in[10];
    float* out = (float*)d_out;

    // workspace layout (4-byte words)
    float* ws        = (float*)d_ws;
    float* dinv      = ws;                                 // 50048
    float* h         = ws + 50048;                         // 3.2M  (h2' / out3)
    float* xcur      = h + N_NODES * HID;                  // 3.2M  (h3')
    float* xs        = xcur + N_NODES * HID;               // 300032
    int*   row_start = (int*)(xs + 300032);                // 50176
    int*   bin_cnt   = row_start + 50176;                  // 256
    int*   bin_start = bin_cnt + 256;                      // 256
    int*   bin_pos   = bin_start + 256;                    // 256
    int*   rec       = bin_pos + 256;                      // 800000
    int*   eidx      = rec + 800000;                       // 800000

    const int* src = ei;
    const int* dst = ei + N_EDGES;

    const int B = 256;
    const int gNF = (N_NODES * HID + B - 1) / B;

    // CSR build (5 dispatches)
    k_init<<<1, B, 0, stream>>>(bin_cnt);
    k_binhist<<<NCHUNK, B, 0, stream>>>(dst, bin_cnt);
    k_binscan<<<1, B, 0, stream>>>(bin_cnt, bin_start, bin_pos, row_start);
    k_part<<<NCHUNK, B, 0, stream>>>(src, dst, bin_pos, rec);
    k_bdf<<<NBINS, B, 0, stream>>>(rec, bin_start, x, row_start, dinv, xs, eidx);

    // layer 1 + mm2 fused -> h2'
    k_l1mm<<<PB, B, 0, stream>>>(xs, row_start, eidx, dinv, W1, b1, W2, h);
    // layer 2 gather + mm3 fused -> h3'
    k_gmm<<<PB, B, 0, stream>>>(h, row_start, eidx, dinv, b2, W3, xcur);
    // layer 3 gather -> out3
    k_gather<<<gNF, B, 0, stream>>>(xcur, row_start, eidx, dinv, b3, h);

    // pool + FC fused (one block per graph, no atomics)
    k_poolfc<<<N_GRAPHS, B, 0, stream>>>(h, batch, Wfc, bfc, out);
}

// Round 13
// 176.102 us; speedup vs baseline: 1.1721x; 1.1652x over previous
//
#include <hip/hip_runtime.h>

#define N_NODES 50000
#define N_EDGES 800000
#define N_GRAPHS 64
#define F_IN 6
#define HID 64
#define EMB 128

#define NBINS 196            // ceil(50000/256) bins of 256 dst nodes
#define EPB 4096             // edges per partition block
#define NCHUNK ((N_EDGES + EPB - 1) / EPB)   // 196
#define EPT (EPB / 256)      // 16 edges per thread

// ---- init: zero bin histogram ----
__global__ void k_init(int* __restrict__ bin_cnt) {
    if (threadIdx.x < NBINS + 4) bin_cnt[threadIdx.x] = 0;
}

// ---- coarse histogram: edges per 256-node dst bin (LDS-aggregated) ----
__global__ void k_binhist(const int* __restrict__ dst, int* __restrict__ bin_cnt) {
    __shared__ int lcnt[NBINS];
    for (int b = threadIdx.x; b < NBINS; b += 256) lcnt[b] = 0;
    __syncthreads();
    int e0 = blockIdx.x * EPB;
#pragma unroll
    for (int t = 0; t < EPT; ++t) {
        int e = e0 + t * 256 + threadIdx.x;
        if (e < N_EDGES) atomicAdd(&lcnt[dst[e] >> 8], 1);
    }
    __syncthreads();
    for (int b = threadIdx.x; b < NBINS; b += 256) {
        int c = lcnt[b];
        if (c) atomicAdd(&bin_cnt[b], c);
    }
}

// ---- scan of 196 bin counts; zero pool accumulators; sentinels ----
__global__ void k_binscan(const int* __restrict__ bin_cnt, int* __restrict__ bin_start,
                          int* __restrict__ bin_pos, int* __restrict__ row_start,
                          float* __restrict__ gsum, float* __restrict__ gcnt) {
    __shared__ int s[256];
    int t = threadIdx.x;
    int v = (t < NBINS) ? bin_cnt[t] : 0;
    s[t] = v;
    __syncthreads();
    for (int off = 1; off < 256; off <<= 1) {
        int o = (t >= off) ? s[t - off] : 0;
        __syncthreads();
        s[t] += o;
        __syncthreads();
    }
    if (t < NBINS) { int st = s[t] - v; bin_start[t] = st; bin_pos[t] = st; }
    if (t == 0) { bin_start[NBINS] = N_EDGES; row_start[N_NODES] = N_EDGES; }
    for (int i = t; i < N_GRAPHS * HID; i += 256) gsum[i] = 0.0f;
    if (t < N_GRAPHS) gcnt[t] = 0.0f;
}

// ---- coarse partition: LDS-ranked, one range-reservation per (block,bin) ----
// rec = (src << 8) | (dst & 255)   [src < 65536]
__global__ void k_part(const int* __restrict__ src, const int* __restrict__ dst,
                       int* __restrict__ bin_pos, int* __restrict__ rec) {
    __shared__ int lcnt[NBINS];
    __shared__ int lbase[NBINS];
    for (int b = threadIdx.x; b < NBINS; b += 256) lcnt[b] = 0;
    __syncthreads();
    int e0 = blockIdx.x * EPB;
    int myBin[EPT], myRank[EPT], myRec[EPT];
#pragma unroll
    for (int t = 0; t < EPT; ++t) {
        int e = e0 + t * 256 + threadIdx.x;
        myBin[t] = -1;
        if (e < N_EDGES) {
            int d = dst[e];
            int s = src[e];
            int b = d >> 8;
            myBin[t] = b;
            myRec[t] = (s << 8) | (d & 255);
            myRank[t] = atomicAdd(&lcnt[b], 1);
        }
    }
    __syncthreads();
    for (int b = threadIdx.x; b < NBINS; b += 256) {
        int c = lcnt[b];
        lbase[b] = c ? atomicAdd(&bin_pos[b], c) : 0;
    }
    __syncthreads();
#pragma unroll
    for (int t = 0; t < EPT; ++t)
        if (myBin[t] >= 0) rec[lbase[myBin[t]] + myRank[t]] = myRec[t];
}

// ---- fused per-bin: degree hist + scan -> row_start/dinv/xs + fine scatter ----
__global__ void k_bdf(const int* __restrict__ rec, const int* __restrict__ bin_start,
                      const float* __restrict__ x, int* __restrict__ row_start,
                      float* __restrict__ dinv, float* __restrict__ xs,
                      int* __restrict__ eidx) {
    __shared__ int ldeg[256];
    __shared__ int rowb[256];
    int t = threadIdx.x;
    ldeg[t] = 0;
    __syncthreads();
    int beg = bin_start[blockIdx.x], end = bin_start[blockIdx.x + 1];
    for (int r = beg + t; r < end; r += 256)
        atomicAdd(&ldeg[rec[r] & 255], 1);
    __syncthreads();
    int v = ldeg[t];
    rowb[t] = v;
    __syncthreads();
    for (int off = 1; off < 256; off <<= 1) {
        int o = (t >= off) ? rowb[t - off] : 0;
        __syncthreads();
        rowb[t] += o;
        __syncthreads();
    }
    int rb = beg + rowb[t] - v;          // exclusive start for local node t
    rowb[t] = rb;                        // own-index write, no hazard
    ldeg[t] = 0;                         // reuse as scatter cursor
    int node = blockIdx.x * 256 + t;
    if (node < N_NODES) {
        row_start[node] = rb;
        float dv = rsqrtf((float)(v + 1));            // +1 = self-loop
        dinv[node] = dv;
#pragma unroll
        for (int k = 0; k < F_IN; ++k) xs[node * F_IN + k] = x[node * F_IN + k] * dv;
    }
    __syncthreads();
    for (int r = beg + t; r < end; r += 256) {
        int rc = rec[r];
        int ld = rc & 255;
        int p = atomicAdd(&ldeg[ld], 1);
        eidx[rowb[ld] + p] = rc >> 8;
    }
}

__device__ __forceinline__ float bcast(float v, int lane) {
    return __int_as_float(__builtin_amdgcn_readlane(__float_as_int(v), lane));
}

#define PB 1280   // persistent blocks for fused layer kernels

// ---- fused layer1+mm2: agg(xs) -> relu(@W1+b1) -> h2' = (out@W2)*dinv ----
__global__ void k_l1mm(const float* __restrict__ xs, const int* __restrict__ row_start,
                       const int* __restrict__ eidx, const float* __restrict__ dinv,
                       const float* __restrict__ W1, const float* __restrict__ b1,
                       const float* __restrict__ W2, float* __restrict__ hout) {
    __shared__ float sW[F_IN * HID];
    __shared__ float sB[HID];
    for (int i = threadIdx.x; i < F_IN * HID; i += 256) sW[i] = W1[i];
    if (threadIdx.x < HID) sB[threadIdx.x] = b1[threadIdx.x];
    __syncthreads();
    int f = threadIdx.x & 63;
    float wk[HID];                       // W2 column f, loaded once per wave
#pragma unroll
    for (int k = 0; k < HID; ++k) wk[k] = W2[k * HID + f];
    bool act = (f < F_IN);
    int wv = blockIdx.x * 4 + (threadIdx.x >> 6);
    for (int node = wv; node < N_NODES; node += PB * 4) {
        int beg = __builtin_amdgcn_readfirstlane(row_start[node]);
        int end = __builtin_amdgcn_readfirstlane(row_start[node + 1]);
        float sum = 0.0f;
        int j = beg;
        for (; j + 8 <= end; j += 8) {
            int s0 = eidx[j+0], s1 = eidx[j+1], s2 = eidx[j+2], s3 = eidx[j+3];
            int s4 = eidx[j+4], s5 = eidx[j+5], s6 = eidx[j+6], s7 = eidx[j+7];
            if (act) {
                float v0 = xs[s0 * F_IN + f], v1 = xs[s1 * F_IN + f];
                float v2 = xs[s2 * F_IN + f], v3 = xs[s3 * F_IN + f];
                float v4 = xs[s4 * F_IN + f], v5 = xs[s5 * F_IN + f];
                float v6 = xs[s6 * F_IN + f], v7 = xs[s7 * F_IN + f];
                sum += ((v0 + v1) + (v2 + v3)) + ((v4 + v5) + (v6 + v7));
            }
        }
        for (; j < end; ++j) {
            int s = eidx[j];
            if (act) sum += xs[s * F_IN + f];
        }
        float dv = dinv[node];
        float val = act ? (sum + xs[node * F_IN + f]) * dv : 0.0f;
        float o = sB[f];
        o = fmaf(bcast(val, 0), sW[0 * HID + f], o);
        o = fmaf(bcast(val, 1), sW[1 * HID + f], o);
        o = fmaf(bcast(val, 2), sW[2 * HID + f], o);
        o = fmaf(bcast(val, 3), sW[3 * HID + f], o);
        o = fmaf(bcast(val, 4), sW[4 * HID + f], o);
        o = fmaf(bcast(val, 5), sW[5 * HID + f], o);
        o = fmaxf(o, 0.0f);              // layer-1 output, lane f
        // mm2 epilogue: h2'[f] = (sum_k o_k * W2[k][f]) * dv
        float a0 = 0.0f, a1 = 0.0f, a2 = 0.0f, a3 = 0.0f;
#pragma unroll
        for (int k = 0; k < HID; k += 4) {
            a0 = fmaf(bcast(o, k + 0), wk[k + 0], a0);
            a1 = fmaf(bcast(o, k + 1), wk[k + 1], a1);
            a2 = fmaf(bcast(o, k + 2), wk[k + 2], a2);
            a3 = fmaf(bcast(o, k + 3), wk[k + 3], a3);
        }
        hout[node * HID + f] = ((a0 + a1) + (a2 + a3)) * dv;
    }
}

// ---- fused gather+mm3: agg(h2') -> relu(+b2) -> h3' = (out@W3)*dinv ----
__global__ void k_gmm(const float* __restrict__ h, const int* __restrict__ row_start,
                      const int* __restrict__ eidx, const float* __restrict__ dinv,
                      const float* __restrict__ b2, const float* __restrict__ W3,
                      float* __restrict__ hout) {
    int f = threadIdx.x & 63;
    float wk[HID];                       // W3 column f
#pragma unroll
    for (int k = 0; k < HID; ++k) wk[k] = W3[k * HID + f];
    float bv = b2[f];
    int wv = blockIdx.x * 4 + (threadIdx.x >> 6);
    for (int node = wv; node < N_NODES; node += PB * 4) {
        int beg = __builtin_amdgcn_readfirstlane(row_start[node]);
        int end = __builtin_amdgcn_readfirstlane(row_start[node + 1]);
        float sum = 0.0f;
        int j = beg;
        for (; j + 8 <= end; j += 8) {
            int s0 = eidx[j+0], s1 = eidx[j+1], s2 = eidx[j+2], s3 = eidx[j+3];
            int s4 = eidx[j+4], s5 = eidx[j+5], s6 = eidx[j+6], s7 = eidx[j+7];
            float v0 = h[s0 * HID + f], v1 = h[s1 * HID + f];
            float v2 = h[s2 * HID + f], v3 = h[s3 * HID + f];
            float v4 = h[s4 * HID + f], v5 = h[s5 * HID + f];
            float v6 = h[s6 * HID + f], v7 = h[s7 * HID + f];
            sum += ((v0 + v1) + (v2 + v3)) + ((v4 + v5) + (v6 + v7));
        }
        if (j + 4 <= end) {
            int s0 = eidx[j+0], s1 = eidx[j+1], s2 = eidx[j+2], s3 = eidx[j+3];
            float v0 = h[s0 * HID + f], v1 = h[s1 * HID + f];
            float v2 = h[s2 * HID + f], v3 = h[s3 * HID + f];
            sum += ((v0 + v1) + (v2 + v3));
            j += 4;
        }
        for (; j < end; ++j) sum += h[eidx[j] * HID + f];
        sum += h[node * HID + f];
        float dv = dinv[node];
        float o = fmaxf(fmaf(sum, dv, bv), 0.0f);    // layer-2 output, lane f
        // mm3 epilogue
        float a0 = 0.0f, a1 = 0.0f, a2 = 0.0f, a3 = 0.0f;
#pragma unroll
        for (int k = 0; k < HID; k += 4) {
            a0 = fmaf(bcast(o, k + 0), wk[k + 0], a0);
            a1 = fmaf(bcast(o, k + 1), wk[k + 1], a1);
            a2 = fmaf(bcast(o, k + 2), wk[k + 2], a2);
            a3 = fmaf(bcast(o, k + 3), wk[k + 3], a3);
        }
        hout[node * HID + f] = ((a0 + a1) + (a2 + a3)) * dv;
    }
}

// ---- final per-node gather: out = relu(dinv*(sum h3'[s] + h3'[d]) + b3) ----
__global__ void k_gather(const float* __restrict__ h, const int* __restrict__ row_start,
                         const int* __restrict__ eidx, const float* __restrict__ dinv,
                         const float* __restrict__ b, float* __restrict__ out) {
    int node = (blockIdx.x * blockDim.x + threadIdx.x) >> 6;
    int f = threadIdx.x & 63;
    if (node >= N_NODES) return;
    int beg = __builtin_amdgcn_readfirstlane(row_start[node]);
    int end = __builtin_amdgcn_readfirstlane(row_start[node + 1]);
    float sum = 0.0f;
    int j = beg;
    for (; j + 8 <= end; j += 8) {
        int s0 = eidx[j+0], s1 = eidx[j+1], s2 = eidx[j+2], s3 = eidx[j+3];
        int s4 = eidx[j+4], s5 = eidx[j+5], s6 = eidx[j+6], s7 = eidx[j+7];
        float v0 = h[s0 * HID + f], v1 = h[s1 * HID + f];
        float v2 = h[s2 * HID + f], v3 = h[s3 * HID + f];
        float v4 = h[s4 * HID + f], v5 = h[s5 * HID + f];
        float v6 = h[s6 * HID + f], v7 = h[s7 * HID + f];
        sum += ((v0 + v1) + (v2 + v3)) + ((v4 + v5) + (v6 + v7));
    }
    if (j + 4 <= end) {
        int s0 = eidx[j+0], s1 = eidx[j+1], s2 = eidx[j+2], s3 = eidx[j+3];
        float v0 = h[s0 * HID + f], v1 = h[s1 * HID + f];
        float v2 = h[s2 * HID + f], v3 = h[s3 * HID + f];
        sum += ((v0 + v1) + (v2 + v3));
        j += 4;
    }
    for (; j < end; ++j) sum += h[eidx[j] * HID + f];
    sum += h[node * HID + f];
    out[node * HID + f] = fmaxf(fmaf(sum, dinv[node], b[f]), 0.0f);
}

// ---- segment sum for global mean pool (batch sorted; register partials) ----
#define POOL_BLOCKS 200
__global__ void k_pool(const float* __restrict__ x, const int* __restrict__ batch,
                       float* __restrict__ gsum, float* __restrict__ gcnt) {
    const int npb = (N_NODES + POOL_BLOCKS - 1) / POOL_BLOCKS;
    int start = blockIdx.x * npb;
    int end = start + npb;
    if (end > N_NODES) end = N_NODES;
    int f = threadIdx.x & 63;
    int grp = threadIdx.x >> 6;
    float sum = 0.0f, cnt = 0.0f;
    int curg = -1;
    for (int node = start + grp; node < end; node += 4) {
        int g = batch[node];
        if (g != curg) {
            if (curg >= 0) {
                atomicAdd(&gsum[curg * HID + f], sum);
                if (f == 0) atomicAdd(&gcnt[curg], cnt);
            }
            curg = g; sum = 0.0f; cnt = 0.0f;
        }
        sum += x[node * HID + f];
        cnt += 1.0f;
    }
    if (curg >= 0) {
        atomicAdd(&gsum[curg * HID + f], sum);
        if (f == 0) atomicAdd(&gcnt[curg], cnt);
    }
}

// ---- final FC ----
__global__ void k_fc(const float* __restrict__ gsum, const float* __restrict__ gcnt,
                     const float* __restrict__ Wfc, const float* __restrict__ bfc,
                     float* __restrict__ out) {
    int gid = blockIdx.x * blockDim.x + threadIdx.x;
    if (gid >= N_GRAPHS * EMB) return;
    int g = gid >> 7;
    int j = gid & 127;
    float inv = 1.0f / fmaxf(gcnt[g], 1.0f);
    float s = bfc[j];
#pragma unroll 8
    for (int k = 0; k < HID; ++k) s += gsum[g * HID + k] * inv * Wfc[k * EMB + j];
    out[gid] = fmaxf(s, 0.0f);
}

extern "C" void kernel_launch(void* const* d_in, const int* in_sizes, int n_in,
                              void* d_out, int out_size, void* d_ws, size_t ws_size,
                              hipStream_t stream) {
    const float* x    = (const float*)d_in[0];
    const int*   ei   = (const int*)d_in[1];
    const int*   batch= (const int*)d_in[2];
    const float* W1   = (const float*)d_in[3];
    const float* b1   = (const float*)d_in[4];
    const float* W2   = (const float*)d_in[5];
    const float* b2   = (const float*)d_in[6];
    const float* W3   = (const float*)d_in[7];
    const float* b3   = (const float*)d_in[8];
    const float* Wfc  = (const float*)d_in[9];
    const float* bfc  = (const float*)d_in[10];
    float* out = (float*)d_out;

    // workspace layout (4-byte words)
    float* ws        = (float*)d_ws;
    float* dinv      = ws;                                 // 50048
    float* h         = ws + 50048;                         // 3.2M  (h2' / out3)
    float* xcur      = h + N_NODES * HID;                  // 3.2M  (h3')
    float* gsum      = xcur + N_NODES * HID;               // 4096
    float* gcnt      = gsum + N_GRAPHS * HID;              // 64
    float* xs        = gcnt + 64;                          // 300032
    int*   row_start = (int*)(xs + 300032);                // 50176
    int*   bin_cnt   = row_start + 50176;                  // 256
    int*   bin_start = bin_cnt + 256;                      // 256
    int*   bin_pos   = bin_start + 256;                    // 256
    int*   rec       = bin_pos + 256;                      // 800000
    int*   eidx      = rec + 800000;                       // 800000

    const int* src = ei;
    const int* dst = ei + N_EDGES;

    const int B = 256;
    const int gNF = (N_NODES * HID + B - 1) / B;

    // CSR build (5 dispatches)
    k_init<<<1, B, 0, stream>>>(bin_cnt);
    k_binhist<<<NCHUNK, B, 0, stream>>>(dst, bin_cnt);
    k_binscan<<<1, B, 0, stream>>>(bin_cnt, bin_start, bin_pos, row_start, gsum, gcnt);
    k_part<<<NCHUNK, B, 0, stream>>>(src, dst, bin_pos, rec);
    k_bdf<<<NBINS, B, 0, stream>>>(rec, bin_start, x, row_start, dinv, xs, eidx);

    // layer 1 + mm2 fused -> h2'
    k_l1mm<<<PB, B, 0, stream>>>(xs, row_start, eidx, dinv, W1, b1, W2, h);
    // layer 2 gather + mm3 fused -> h3'
    k_gmm<<<PB, B, 0, stream>>>(h, row_start, eidx, dinv, b2, W3, xcur);
    // layer 3 gather -> out3
    k_gather<<<gNF, B, 0, stream>>>(xcur, row_start, eidx, dinv, b3, h);

    // pool + FC (parallel 200-block partial sums, then tiny FC)
    k_pool<<<POOL_BLOCKS, B, 0, stream>>>(h, batch, gsum, gcnt);
    k_fc<<<(N_GRAPHS * EMB + B - 1) / B, B, 0, stream>>>(gsum, gcnt, Wfc, bfc, out);
}